// Round 1
// 165.946 us; speedup vs baseline: 1.0398x; 1.0398x over previous
//
#include <hip/hip_runtime.h>

#define TDIM 128

__device__ __forceinline__ float u2f(unsigned int u) {
  union { unsigned int u; float f; } w; w.u = u; return w.f;
}
__device__ __forceinline__ float bf2f(unsigned short v) {
  return u2f(((unsigned int)v) << 16);
}
__device__ __forceinline__ unsigned short f2bf(float x) {
  union { float f; unsigned int u; } w; w.f = x;
  unsigned int u = w.u;
  u += 0x7fffu + ((u >> 16) & 1u);   // round-to-nearest-even
  return (unsigned short)(u >> 16);
}

// One block per output row r -> (l, m, pair (l1,l2)).
// out[r*16384 + t1*128 + t2] = sum_q C_q * clms[i0+q, t1] * clms[j0-q, t2]
//
// Decode is closed-form (no trivalid loops):
//   rows(l) = (2l+1)*cnt(l), cum = {0,8,71,226,492,870,1343,1876,2416}
//   for fixed (l,l1): valid l2 = contiguous range [|l1-l|, min(7,l1+l)]
// Only the two 15x128 windows are staged (16 KB LDS); the CG coefficient is
// folded into the B window at staging time, so the hot loop is pure
// ds_read_b32(broadcast, literal offset) + 4 FMA per (q, t1).
__global__ __launch_bounds__(256, 4)
void cg_kernel(const void* __restrict__ clms_raw,
               const void* __restrict__ C_raw,
               void* __restrict__ out_raw) {
  __shared__ float sa[16 * TDIM];   // sa[q][t] = clms_f32[i0+q][t]
  __shared__ float sb[16 * TDIM];   // sb[q][t] = C_q * clms_f32[j0-q][t]

  const int tid = threadIdx.x;

  // ---- dtype sniff (uniform across threads/blocks) ----
  const unsigned int* cw = (const unsigned int*)clms_raw;
  int nbf = 0;
  #pragma unroll
  for (int i = 0; i < 32; ++i) {
    unsigned int e = (cw[i] >> 7) & 0xFFu;
    nbf += (e >= 110u && e <= 135u) ? 1 : 0;
  }
  const bool in_bf16 = (nbf >= 16);
  const bool c_bf16 = ((*(const unsigned int*)C_raw) & 0xffffu) == 0x3f80u;

  // ---- decode blockIdx -> (l, m, l1, l2); uniform, branch-free scalar ----
  const int r = blockIdx.x;
  int l = 0, cum = 0, pc = 8;
  if (r >= 8)    { l = 1; cum = 8;    pc = 21; }
  if (r >= 71)   { l = 2; cum = 71;   pc = 31; }
  if (r >= 226)  { l = 3; cum = 226;  pc = 38; }
  if (r >= 492)  { l = 4; cum = 492;  pc = 42; }
  if (r >= 870)  { l = 5; cum = 870;  pc = 43; }
  if (r >= 1343) { l = 6; cum = 1343; pc = 41; }
  if (r >= 1876) { l = 7; cum = 1876; pc = 36; }
  const int rem = r - cum;
  const int mi  = rem / pc;          // one uniform int division
  const int m   = mi - l;
  int pp = rem - mi * pc;
  int l1 = 0, l2 = 0, found = 0;
  #pragma unroll
  for (int a = 0; a < 8; ++a) {      // pair p -> (l1,l2), contiguous-l2 ranges
    int d = a - l; if (d < 0) d = -d;
    int hi = a + l; if (hi > 7) hi = 7;
    int na = hi - d + 1;
    if (!found && pp < na) { l1 = a; l2 = d + pp; found = 1; }
    if (!found) pp -= na;
  }

  const int m1lo = (-l1 > m - l2) ? -l1 : (m - l2);
  const int m1hi = ( l1 < m + l2) ?  l1 : (m + l2);
  const int nnz = m1hi - m1lo + 1;           // 1..15, uniform
  const int i0 = l1 * (l1 + 1) + m1lo;       // A rows: i0+q
  const int j0 = l2 * (l2 + 1) + (m - m1lo); // B rows: j0-q
  const int k0 = l * (l + 1) + m;

  // ---- stage the two 15x128 windows (B pre-scaled by its CG coefficient) ----
  // 30 rows x 64 (2-element) columns = 1920 units; one row per wave-pass ->
  // coalesced 256B(bf16)/512B(f32) global reads, conflict-free float2 writes.
  #pragma unroll
  for (int kk = 0; kk < 8; ++kk) {
    const int u = tid + 256 * kk;
    if (u < 1920) {                   // wave-uniform guard
      const int row  = u >> 6;        // 0..29, uniform per wave
      const int lane = u & 63;
      const int isB  = row >= 15;
      const int q    = isB ? row - 15 : row;
      const int qc   = (q < nnz) ? q : 0;        // clamp for address validity
      const int gr   = isB ? (j0 - qc) : (i0 + qc);
      float f0, f1;
      if (in_bf16) {
        unsigned int v = ((const unsigned int*)clms_raw)[gr * 64 + lane];
        f0 = u2f(v << 16); f1 = u2f(v & 0xffff0000u);
      } else {
        float2 v = ((const float2*)clms_raw)[gr * 64 + lane];
        f0 = v.x; f1 = v.y;
      }
      if (isB) {
        float cq = 0.0f;
        if (q < nnz) {                // wave-uniform; broadcast C load
          int ci = (k0 * 64 + i0 + q) * 64 + (j0 - q);
          cq = c_bf16 ? bf2f(((const unsigned short*)C_raw)[ci])
                      : ((const float*)C_raw)[ci];
        }
        f0 *= cq; f1 *= cq;           // q>=nnz rows become exactly 0
        *(float2*)&sb[q * TDIM + lane * 2] = make_float2(f0, f1);
      } else {
        *(float2*)&sa[q * TDIM + lane * 2] = make_float2(f0, f1);
      }
    }
  }
  __syncthreads();

  // ---- hot loop: acc[t1][t2] += sa[q][t1] * sb[q][t2] ----
  const int tx = tid & 31;
  const int ty = tid >> 5;
  float4 b[15];
  #pragma unroll
  for (int q = 0; q < 15; ++q)        // ds_read_b128, literal offset q*512
    b[q] = *(const float4*)&sb[q * TDIM + tx * 4];

  const unsigned long long outbase =
      (unsigned long long)r * (TDIM * TDIM) + (unsigned int)(tx * 4);

  if (in_bf16) {
    unsigned short* out = (unsigned short*)out_raw;
    for (int s0 = 0; s0 < 4; ++s0) {
      const int t1b = ty + 32 * s0;
      float4 acc[4];
      #pragma unroll
      for (int d = 0; d < 4; ++d) acc[d] = make_float4(0.f, 0.f, 0.f, 0.f);
      #pragma unroll
      for (int q = 0; q < 15; ++q) {
        if (q < nnz) {                // uniform -> scalar branch
          #pragma unroll
          for (int d = 0; d < 4; ++d) {
            float a = sa[q * TDIM + t1b + 8 * d];  // 2-way broadcast read
            acc[d].x += a * b[q].x;
            acc[d].y += a * b[q].y;
            acc[d].z += a * b[q].z;
            acc[d].w += a * b[q].w;
          }
        }
      }
      #pragma unroll
      for (int d = 0; d < 4; ++d) {
        ushort4 o;
        o.x = f2bf(acc[d].x); o.y = f2bf(acc[d].y);
        o.z = f2bf(acc[d].z); o.w = f2bf(acc[d].w);
        *(ushort4*)(out + outbase + (unsigned long long)((t1b + 8 * d) * TDIM)) = o;
      }
    }
  } else {
    float* out = (float*)out_raw;
    for (int s0 = 0; s0 < 4; ++s0) {
      const int t1b = ty + 32 * s0;
      float4 acc[4];
      #pragma unroll
      for (int d = 0; d < 4; ++d) acc[d] = make_float4(0.f, 0.f, 0.f, 0.f);
      #pragma unroll
      for (int q = 0; q < 15; ++q) {
        if (q < nnz) {
          #pragma unroll
          for (int d = 0; d < 4; ++d) {
            float a = sa[q * TDIM + t1b + 8 * d];
            acc[d].x += a * b[q].x;
            acc[d].y += a * b[q].y;
            acc[d].z += a * b[q].z;
            acc[d].w += a * b[q].w;
          }
        }
      }
      #pragma unroll
      for (int d = 0; d < 4; ++d)
        *(float4*)(out + outbase + (unsigned long long)((t1b + 8 * d) * TDIM)) = acc[d];
    }
  }
}

extern "C" void kernel_launch(void* const* d_in, const int* in_sizes, int n_in,
                              void* d_out, int out_size, void* d_ws, size_t ws_size,
                              hipStream_t stream) {
  (void)in_sizes; (void)n_in; (void)d_ws; (void)ws_size;
  const int nrows = out_size / (TDIM * TDIM);   // 2416 for L=7, T=128
  cg_kernel<<<nrows, 256, 0, stream>>>(d_in[0], d_in[1], d_out);
}